// Round 2
// baseline (306.893 us; speedup 1.0000x reference)
//
#include <hip/hip_runtime.h>
#include <hip/hip_bf16.h>

// BasicAttention: B=4, S=2048, E=1024, QD=VD=1024, fp32 in/out.
// Pipeline (all bf16 MFMA, fp32 accum):
//   1. cast_x:    x fp32 [8192,1024] -> xb bf16
//   2. cast_wt:   Wq/Wk/Wv fp32 [E,D] -> Wt bf16 [D,E] (transposed -> B^T GEMMs)
//   3. gemm256<0>: FUSED Q+K projection (M=8192, N=2048 over Wq|Wk panels),
//                  256 blocks, 8-phase 256^2 schedule -> Qb, Kb (+bias)
//   4. gemm_bt<1>: V projection, TRANSPOSED store Vt[b][d][s]   (128^2 kernel)
//   5. gemm256<4>: S = Q@K^T*(1/1024) -> bf16, 256 blocks, 8-phase
//   6. softmax_rows: P = softmax(mask ? S : -1e30) -> bf16 (mask read once)
//   7. gemm_bt<3>: out = P@Vt^T -> fp32 (128 blocks only at 256^2 -> keep 128^2)
//
// R10->R11: R10's 8-phase ran at 53.5us (WORSE than 128^2's 41.5) with
// MfmaUtil 24% and 3.1M bank conflicts. Root causes:
// (a) ::: "memory" clobbers on the waitcnt asms forced the backend to drain
//     vmcnt at every phase (~2000cy/phase = full HBM latency) -- the exact
//     anti-pattern the counted-vmcnt schedule exists to avoid. Fixed: bare
//     asm volatile waits + sched_barrier(0) phase punctuation (rule #18 /
//     HK technique). Compiler's own counted lgkmcnt waits cover ds->MFMA deps.
// (b) epilogue read had lanes at 64B stride -> 8-way LDS conflicts. Fixed:
//     one wave reads one row (64 lanes x float4 consecutive, conflict-free),
//     bf16x4 coalesced global store.
//
// Workspace (MB): xb@0(16) Wt@16(6) Qb@22(16) Kb@38(16) Vt@54(16) Sf@70(32,bf16);
// Pb aliases @22(32). Total 102 MB. (Tail prefetch over-reads stay inside ws.)

typedef __bf16 bf16x8 __attribute__((ext_vector_type(8)));
typedef __bf16 bf16x4 __attribute__((ext_vector_type(4)));
typedef float f32x4 __attribute__((ext_vector_type(4)));

#define BM 128
#define BN 128
#define BK 64

// async global->LDS, 16B per lane; LDS dest = wave-uniform base + lane*16
__device__ inline void glds16(const __bf16* g, __bf16* l) {
    __builtin_amdgcn_global_load_lds(
        (const __attribute__((address_space(1))) unsigned int*)g,
        (__attribute__((address_space(3))) unsigned int*)l,
        16, 0, 0);
}

// ============ 256x256 8-phase GEMM: C = A @ B^T (both row-major bf16) ========
// EPI 0: dual bf16 out + bias (fused QK proj: col0<1024 -> C0/bias0 else C1/bias1)
// EPI 4: bf16 out * scale (scores), batched by blockIdx.z
template <int EPI>
__global__ __launch_bounds__(512, 2) void gemm256(
    const __bf16* __restrict__ A, const __bf16* __restrict__ B,
    __bf16* __restrict__ C0, __bf16* __restrict__ C1,
    const float* __restrict__ bias0, const float* __restrict__ bias1,
    int K, int ldc, float scale, long sA, long sB, long sC)
{
    A += (long)blockIdx.z * sA;
    B += (long)blockIdx.z * sB;

    __shared__ __align__(16) char sm[131072];   // 2 x (A 32K + B 32K)

    const int t = threadIdx.x;
    const int w = t >> 6, l = t & 63;
    const int wm = w >> 2, wn = w & 3;          // 2M x 4N waves, 128x64 each
    const int row0 = blockIdx.x * 256, col0 = blockIdx.y * 256;
    const int srow = l >> 3;                     // row within 8-row chunk
    const int skel = (((l & 7) ^ srow) & 7) * 8; // swizzled global chunk offset
    const int lm = l & 15, g16 = l >> 4, sx = lm & 7;

    const __bf16* Ap = A + (size_t)row0 * K;
    const __bf16* Bp = B + (size_t)col0 * K;

    f32x4 acc[8][4];
#pragma unroll
    for (int i = 0; i < 8; i++)
#pragma unroll
        for (int j = 0; j < 4; j++) acc[i][j] = (f32x4){0.f, 0.f, 0.f, 0.f};

    // stage one half-tile (128 rows x 64 k) = 16 chunks of (8 rows x 64 k);
    // each wave covers chunks w*2, w*2+1 -> 2 glds16 per thread.
    auto stageHalf = [&](int mat, int h, int buf, int kt) {
        const __bf16* G = mat ? Bp : Ap;
        char* base = sm + (buf << 16) + mat * 32768 + h * 16384;
#pragma unroll
        for (int i = 0; i < 2; i++) {
            const int c = w * 2 + i;
            glds16(G + (size_t)(h * 128 + c * 8 + srow) * K + kt + skel,
                   (__bf16*)(base + c * 1024));
        }
    };

    bf16x8 a03[4][2], a47[4][2], b01[2][2], b23[2][2];

    auto rdA = [&](bf16x8 (&d)[4][2], int buf, int half) {
        const char* Ab = sm + (buf << 16);
#pragma unroll
        for (int mt = 0; mt < 4; mt++) {
            const int r = wm * 128 + half * 64 + mt * 16 + lm;
#pragma unroll
            for (int ks = 0; ks < 2; ks++)
                d[mt][ks] = *(const bf16x8*)(Ab + r * 128 + ((((ks << 2) | g16) ^ sx) << 4));
        }
    };
    auto rdB = [&](bf16x8 (&d)[2][2], int buf, int half) {
        const char* Bb = sm + (buf << 16) + 32768;
#pragma unroll
        for (int nt = 0; nt < 2; nt++) {
            const int r = wn * 64 + half * 32 + nt * 16 + lm;
#pragma unroll
            for (int ks = 0; ks < 2; ks++)
                d[nt][ks] = *(const bf16x8*)(Bb + r * 128 + ((((ks << 2) | g16) ^ sx) << 4));
        }
    };
    auto mf8 = [&](bf16x8 (&Af)[4][2], bf16x8 (&Bf)[2][2], int mo, int no) {
#pragma unroll
        for (int ks = 0; ks < 2; ks++)
#pragma unroll
            for (int mt = 0; mt < 4; mt++)
#pragma unroll
                for (int nt = 0; nt < 2; nt++)
                    acc[mo + mt][no + nt] = __builtin_amdgcn_mfma_f32_16x16x32_bf16(
                        Af[mt][ks], Bf[nt][ks], acc[mo + mt][no + nt], 0, 0, 0);
    };

    // Bare waits (NO memory clobber -- a clobber forces the backend to drain
    // vmcnt at each use, serializing the pipeline). sched_barrier(0) pins the
    // phase structure instead (rule #18 / HK pattern).
#define SB    __builtin_amdgcn_sched_barrier(0)
#define BAR   __builtin_amdgcn_s_barrier()
#define VM4   asm volatile("s_waitcnt vmcnt(4)")

    // prologue: tile0 fully + tile1 A-halves; vmcnt(4) -> tile0's 8 loads
    // landed, tile1's 4 A-loads in flight (steady-state entry condition)
    stageHalf(0, 0, 0, 0); stageHalf(0, 1, 0, 0);
    stageHalf(1, 0, 0, 0); stageHalf(1, 1, 0, 0);
    stageHalf(0, 0, 1, 64); stageHalf(0, 1, 1, 64);
    SB; VM4; BAR; SB;

    const int nkt = K >> 6;
    for (int tt = 0; tt < nkt; tt += 2) {
#pragma unroll
        for (int sub = 0; sub < 2; sub++) {
            const int tcur = tt + sub;
            const int buf = sub;                   // tile parity == sub (tt even)
            const int ktn1 = (tcur + 1) << 6;      // next tile's B halves
            const int ktn2 = (tcur + 2) << 6;      // tile-after-next's A halves
            // ph1: Q00 (mt0-3 x nt0-1)
            rdA(a03, buf, 0); rdB(b01, buf, 0);
            stageHalf(1, 0, buf ^ 1, ktn1);
            SB; BAR; SB;
            __builtin_amdgcn_s_setprio(1); mf8(a03, b01, 0, 0); __builtin_amdgcn_s_setprio(0);
            SB; BAR; SB;
            // ph2: Q10 (mt4-7 x nt0-1)
            rdA(a47, buf, 1); rdB(b23, buf, 1);
            stageHalf(1, 1, buf ^ 1, ktn1);
            SB; BAR; SB;
            __builtin_amdgcn_s_setprio(1); mf8(a47, b01, 4, 0); __builtin_amdgcn_s_setprio(0);
            SB; BAR; SB;
            // ph3: Q01 (mt0-3 x nt2-3); buf's A-half0 reads all done -> restage
            stageHalf(0, 0, buf, ktn2);
            SB; BAR; SB;
            __builtin_amdgcn_s_setprio(1); mf8(a03, b23, 0, 2); __builtin_amdgcn_s_setprio(0);
            SB; BAR; SB;
            // ph4: Q11 (mt4-7 x nt2-3); vmcnt(4) vouches next tile fully landed
            stageHalf(0, 1, buf, ktn2);
            SB; BAR; SB;
            __builtin_amdgcn_s_setprio(1); mf8(a47, b23, 4, 2); __builtin_amdgcn_s_setprio(0);
            SB; VM4; BAR; SB;
        }
    }
#undef SB
#undef BAR
#undef VM4

    // ---- epilogue: stage C through LDS (buf0 region; in-flight tail garbage
    // targets buf1 only). Read: one wave per row (64 lanes x float4 consecutive
    // = conflict-free), bf16x4 coalesced global store. ----
    float* smC = (float*)sm;                 // [32][260] fp32 view
    const int rl = g16 * 4;
    float breg[4];
    __bf16* Cout;
    int cbase;
    if (EPI == 0) {
        const bool isQ = (col0 < 1024);
        const float* bias = isQ ? bias0 : bias1;
        cbase = col0 & 1023;
        Cout = isQ ? C0 : C1;
#pragma unroll
        for (int nt = 0; nt < 4; nt++) breg[nt] = bias[cbase + wn * 64 + nt * 16 + lm];
    } else {
        Cout = C0 + (long)blockIdx.z * sC;
        cbase = col0;
    }

#pragma unroll
    for (int mt = 0; mt < 8; mt++) {
        // write: 32 rows (2 wm-groups of 16) x 256 cols; C/D layout col=lane&15,
        // row=(lane>>4)*4+i [m91-verified]; lanes write consecutive cols -> ok
#pragma unroll
        for (int nt = 0; nt < 4; nt++)
#pragma unroll
            for (int i = 0; i < 4; i++) {
                const int lr = wm * 16 + rl + i;
                const int c = wn * 64 + nt * 16 + lm;
                float v = acc[mt][nt][i];
                if (EPI == 0) v += breg[nt];
                if (EPI == 4) v *= scale;
                smC[lr * 260 + c] = v;
            }
        __syncthreads();
#pragma unroll
        for (int r = 0; r < 4; r++) {
            const int rr = r * 8 + w;                    // wave reads one row
            const float4 v4 = *(const float4*)&smC[rr * 260 + l * 4];
            bf16x4 o = {(__bf16)v4.x, (__bf16)v4.y, (__bf16)v4.z, (__bf16)v4.w};
            const int gr = row0 + (rr >> 4) * 128 + mt * 16 + (rr & 15);
            *(bf16x4*)&Cout[(size_t)gr * ldc + cbase + l * 4] = o;
        }
        __syncthreads();
    }
}

// ================= 128x128 GEMM (kept for V-proj transpose + PV) =============
// C = A @ B^T. A: [M,K] bf16 row-major. B: [N,K] bf16 row-major (B^T input).
// EPI 1: V transposed bf16 store (+bias)      EPI 3: Cf = acc (fp32)
template <int EPI>
__global__ __launch_bounds__(256) void gemm_bt(
    const __bf16* __restrict__ A, const __bf16* __restrict__ B,
    float* __restrict__ Cf, __bf16* __restrict__ Cb,
    const float* __restrict__ bias,
    int M, int N, int K, float scale,
    long sA, long sB, long sC)
{
    A += (long)blockIdx.z * sA;
    B += (long)blockIdx.z * sB;
    if (EPI == 3) Cf += (long)blockIdx.z * sC;
    if (EPI == 4) Cb += (long)blockIdx.z * sC;

    __shared__ __align__(16) char smraw[65536];   // 2 x (A 16K + B 16K)
    float* smC = (float*)smraw;                   // [32][132] epilogue view

    const int t = threadIdx.x;
    const int w = t >> 6;          // wave 0..3
    const int l = t & 63;          // lane
    const int row0 = blockIdx.x * BM;
    const int col0 = blockIdx.y * BN;
    const int wm = (w >> 1) * 64;  // wave's 64x64 quadrant
    const int wn = (w & 1) * 64;

    const int srow = l >> 3;                       // 0..7 row within chunk
    const int skel = (((l & 7) ^ srow) & 7) * 8;   // SWIZZLED global chunk offset

    const int lm = l & 15;
    const int g16 = l >> 4;        // 16-lane group 0..3
    const int sx = lm & 7;         // row swizzle key

    f32x4 acc[4][4];
#pragma unroll
    for (int i = 0; i < 4; i++)
#pragma unroll
        for (int j = 0; j < 4; j++) acc[i][j] = (f32x4){0.f, 0.f, 0.f, 0.f};

    auto stage = [&](int buf, int kt) {
        __bf16* sA = (__bf16*)(smraw + buf * 32768);
        __bf16* sB = sA + BM * BK;
#pragma unroll
        for (int i = 0; i < 4; i++) {
            const int chunk = i * 4 + w;
            const int r = chunk * 8 + srow;
            glds16(A + (size_t)(row0 + r) * K + kt + skel, &sA[chunk * 512]);
            glds16(B + (size_t)(col0 + r) * K + kt + skel, &sB[chunk * 512]);
        }
    };

    stage(0, 0);                 // prologue
    int cur = 0;
    for (int kt = 0; kt < K; kt += BK) {
        __syncthreads();         // buf[cur] loads landed during prev compute
        if (kt + BK < K) stage(cur ^ 1, kt + BK);

        const __bf16* sA = (const __bf16*)(smraw + cur * 32768);
        const __bf16* sB = sA + BM * BK;
#pragma unroll
        for (int ks = 0; ks < 2; ks++) {
            bf16x8 af[4], bg[4];
            const int p = ((ks * 4 + g16) ^ sx) * 8;   // swizzled position
#pragma unroll
            for (int mt = 0; mt < 4; mt++)
                af[mt] = *(const bf16x8*)&sA[(wm + mt * 16 + lm) * BK + p];
#pragma unroll
            for (int nt = 0; nt < 4; nt++)
                bg[nt] = *(const bf16x8*)&sB[(wn + nt * 16 + lm) * BK + p];
#pragma unroll
            for (int mt = 0; mt < 4; mt++)
#pragma unroll
                for (int nt = 0; nt < 4; nt++)
                    acc[mt][nt] = __builtin_amdgcn_mfma_f32_16x16x32_bf16(
                        af[mt], bg[nt], acc[mt][nt], 0, 0, 0);
        }
        cur ^= 1;
    }
    __syncthreads();             // all reads done before smC aliasing

    const int rl = (l >> 4) * 4;
    float breg[4];
    if (EPI <= 1) {
#pragma unroll
        for (int nt = 0; nt < 4; nt++) breg[nt] = bias[col0 + wn + nt * 16 + lm];
    }
#pragma unroll
    for (int mt = 0; mt < 4; mt++) {
#pragma unroll
        for (int nt = 0; nt < 4; nt++)
#pragma unroll
            for (int i = 0; i < 4; i++) {
                const int lr = (w >> 1) * 16 + rl + i;   // 0..31
                const int c  = wn + nt * 16 + lm;        // 0..127
                float v = acc[mt][nt][i];
                if (EPI <= 1) v += breg[nt];
                if (EPI == 4) v *= scale;
                smC[lr * 132 + c] = v;
            }
        __syncthreads();

        if (EPI == 1) {
            // transposed store: Vt[batch][d][s], 64B segments per d
#pragma unroll
            for (int k = 0; k < 4; k++) {
                const int d  = (t >> 3) + 32 * k;        // 0..127
                const int sc = (t & 7) * 4;              // 0..28 (stays in 16-group)
                const int gr = row0 + mt * 16 + (sc & 15) + (sc >> 4) * 64;
                bf16x4 o;
#pragma unroll
                for (int j = 0; j < 4; j++) o[j] = (__bf16)smC[(sc + j) * 132 + d];
                *(bf16x4*)&Cb[(size_t)(gr >> 11) * ((size_t)N * 2048)
                              + (size_t)(col0 + d) * 2048 + (gr & 2047)] = o;
            }
        } else {
#pragma unroll
            for (int k = 0; k < 4; k++) {
                const int lr = (t >> 5) + 8 * k;         // 0..31
                const int c4 = (t & 31) * 4;             // 0..124
                const int gr = row0 + mt * 16 + (lr & 15) + (lr >> 4) * 64;
                const float4 v = *(const float4*)&smC[lr * 132 + c4];
                if (EPI == 0 || EPI == 4) {
                    bf16x4 o = {(__bf16)v.x, (__bf16)v.y, (__bf16)v.z, (__bf16)v.w};
                    *(bf16x4*)&Cb[(size_t)gr * N + col0 + c4] = o;
                } else {
                    *(float4*)&Cf[(size_t)gr * N + col0 + c4] = v;
                }
            }
        }
        __syncthreads();
    }
}

__global__ __launch_bounds__(256) void cast_x(const float* __restrict__ X, __bf16* __restrict__ Y) {
    const size_t i = (size_t)blockIdx.x * 256 + threadIdx.x;
    const float4* X4 = (const float4*)X;
    const float4 a = X4[i * 2], b = X4[i * 2 + 1];
    bf16x8 o = {(__bf16)a.x, (__bf16)a.y, (__bf16)a.z, (__bf16)a.w,
                (__bf16)b.x, (__bf16)b.y, (__bf16)b.z, (__bf16)b.w};
    ((bf16x8*)Y)[i] = o;
}

// W [E=1024, D=1024] fp32 -> Wt [D, E] bf16, z selects q/k/v
__global__ void cast_wt(const float* __restrict__ Wq, const float* __restrict__ Wk,
                        const float* __restrict__ Wv, __bf16* __restrict__ Wt) {
    const float* W = blockIdx.z == 0 ? Wq : (blockIdx.z == 1 ? Wk : Wv);
    __bf16* O = Wt + (size_t)blockIdx.z * 1024 * 1024;
    __shared__ float tile[32][33];
    const int tx = threadIdx.x, ty = threadIdx.y;
    const int d0 = blockIdx.x * 32, e0 = blockIdx.y * 32;
#pragma unroll
    for (int j = 0; j < 32; j += 8)
        tile[ty + j][tx] = W[(size_t)(e0 + ty + j) * 1024 + d0 + tx];
    __syncthreads();
#pragma unroll
    for (int j = 0; j < 32; j += 8)
        O[(size_t)(d0 + ty + j) * 1024 + e0 + tx] = (__bf16)tile[tx][ty + j];
}

// one block per row of 2048; S bf16 + mask int32 -> P bf16
__global__ __launch_bounds__(256) void softmax_rows(const __bf16* __restrict__ S,
                                                    const int* __restrict__ mask,
                                                    __bf16* __restrict__ P) {
    const size_t row = blockIdx.x;
    const int t = threadIdx.x;
    const int w = t >> 6, l = t & 63;
    const bf16x8 s8 = ((const bf16x8*)(S + row * 2048))[t];
    const int4 mk0 = ((const int4*)(mask + row * 2048))[t * 2];
    const int4 mk1 = ((const int4*)(mask + row * 2048))[t * 2 + 1];
    float v[8];
    v[0] = mk0.x ? (float)s8[0] : -1e30f;
    v[1] = mk0.y ? (float)s8[1] : -1e30f;
    v[2] = mk0.z ? (float)s8[2] : -1e30f;
    v[3] = mk0.w ? (float)s8[3] : -1e30f;
    v[4] = mk1.x ? (float)s8[4] : -1e30f;
    v[5] = mk1.y ? (float)s8[5] : -1e30f;
    v[6] = mk1.z ? (float)s8[6] : -1e30f;
    v[7] = mk1.w ? (float)s8[7] : -1e30f;
    float m = v[0];
#pragma unroll
    for (int i = 1; i < 8; i++) m = fmaxf(m, v[i]);
#pragma unroll
    for (int off = 32; off; off >>= 1) m = fmaxf(m, __shfl_xor(m, off, 64));
    __shared__ float rm[4], rs[4];
    if (l == 0) rm[w] = m;
    __syncthreads();
    m = fmaxf(fmaxf(rm[0], rm[1]), fmaxf(rm[2], rm[3]));
    float e[8], sum = 0.f;
#pragma unroll
    for (int i = 0; i < 8; i++) { e[i] = __expf(v[i] - m); sum += e[i]; }
#pragma unroll
    for (int off = 32; off; off >>= 1) sum += __shfl_xor(sum, off, 64);
    if (l == 0) rs[w] = sum;
    __syncthreads();
    const float inv = 1.f / (rs[0] + rs[1] + rs[2] + rs[3]);
    bf16x8 o;
#pragma unroll
    for (int i = 0; i < 8; i++) o[i] = (__bf16)(e[i] * inv);
    ((bf16x8*)(P + row * 2048))[t] = o;
}

extern "C" void kernel_launch(void* const* d_in, const int* in_sizes, int n_in,
                              void* d_out, int out_size, void* d_ws, size_t ws_size,
                              hipStream_t stream) {
    const float* x  = (const float*)d_in[0];
    const int* mask = (const int*)d_in[1];
    const float* Wq = (const float*)d_in[2];
    const float* bq = (const float*)d_in[3];
    const float* Wk = (const float*)d_in[4];
    const float* bk = (const float*)d_in[5];
    const float* Wv = (const float*)d_in[6];
    const float* bv = (const float*)d_in[7];
    float* out = (float*)d_out;

    char* ws = (char*)d_ws;
    __bf16* xb = (__bf16*)(ws);                        // 16 MB
    __bf16* Wt = (__bf16*)(ws + (16ull << 20));        //  6 MB
    __bf16* Qb = (__bf16*)(ws + (22ull << 20));        // 16 MB
    __bf16* Kb = (__bf16*)(ws + (38ull << 20));        // 16 MB
    __bf16* Vt = (__bf16*)(ws + (54ull << 20));        // 16 MB
    __bf16* Sf = (__bf16*)(ws + (70ull << 20));        // 32 MB (bf16)
    __bf16* Pb = (__bf16*)(ws + (22ull << 20));        // 32 MB, aliases Qb+Kb (dead)

    cast_x<<<4096, 256, 0, stream>>>(x, xb);
    cast_wt<<<dim3(32, 32, 3), dim3(32, 8), 0, stream>>>(Wq, Wk, Wv, Wt);

    // fused Q+K projection: M=8192, N=2048 (Wq|Wk panels), K=1024, 256 blocks
    gemm256<0><<<dim3(32, 8, 1), 512, 0, stream>>>(xb, Wt, Qb, Kb, bq, bk,
                                                   1024, 1024, 1.f, 0, 0, 0);
    // V projection with transposed store (128^2 kernel)
    gemm_bt<1><<<dim3(64, 8, 1), 256, 0, stream>>>(xb, Wt + (2u << 20), nullptr, Vt, bv,
                                                   8192, 1024, 1024, 1.f, 0, 0, 0);

    // scores: per batch, M=N=2048, K=1024 -> bf16 Sf, scale folded, 256 blocks
    gemm256<4><<<dim3(8, 8, 4), 512, 0, stream>>>(Qb, Kb, Sf, nullptr, nullptr, nullptr,
                                                  1024, 2048, 1.0f / 1024.0f,
                                                  2048L * 1024, 2048L * 1024,
                                                  2048L * 2048);

    softmax_rows<<<8192, 256, 0, stream>>>(Sf, mask, Pb);

    // out = P @ V: per batch, M=2048, N=1024, K=2048
    gemm_bt<3><<<dim3(16, 8, 4), 256, 0, stream>>>(Pb, Vt, out, nullptr, nullptr,
                                                   2048, 1024, 2048, 1.f,
                                                   2048L * 2048, 1024L * 2048,
                                                   2048L * 1024);
}

// Round 4
// 284.518 us; speedup vs baseline: 1.0786x; 1.0786x over previous
//
#include <hip/hip_runtime.h>
#include <hip/hip_bf16.h>

// BasicAttention: B=4, S=2048, E=1024, QD=VD=1024, fp32 in/out.
// Pipeline (all bf16 MFMA, fp32 accum), 5 launches:
//   1. cast_all:  x fp32 -> xb bf16  AND  Wq/Wk/Wv fp32 -> Wt bf16 [3072,1024]
//                 (transposed), fused in one dispatch (block-role branch)
//   2. gemm_bt<2>: FUSED Q/K/V projection, grid (64,24): blockIdx.y>>3 picks
//                 role: 0 -> Qb (+bq), 1 -> Kb (+bk), 2 -> Vt TRANSPOSED (+bv)
//   3. gemm_bt<4>: S = Q@K^T*(1/1024) -> bf16 Sf (no mask here)
//   4. softmax_rows: P = softmax(mask ? S : -1e30) -> bf16 (mask read once)
//   5. gemm_bt<3>: out = P@Vt^T -> fp32
//
// R12->R13: R12 (8-phase gemm256 + opaque-asm ds_read) killed the container
// twice -> gemm256 dropped entirely; all GEMMs back on the R9-proven 128^2
// kernel (41.5us scores, zero bank conflicts, 830 TF). New lever: R9/R11
// rocprof shows kernel-time sum ~177-205us vs wall ~299-307us -> ~100-120us
// residual consistent with ~12-15us PER-LAUNCH overhead x 8 launches.
// This round cuts 8 launches -> 5 (fused QKV projection via runtime role
// branch; fused casts). Per-block GEMM work is byte-identical to R9.
//
// Workspace (MB): xb@0(16) Wt@16(6) Qb@22(16) Kb@38(16) Vt@54(16) Sf@70(32,bf16);
// Pb aliases @22(32). Total 102 MB.

typedef __bf16 bf16x8 __attribute__((ext_vector_type(8)));
typedef __bf16 bf16x4 __attribute__((ext_vector_type(4)));
typedef float f32x4 __attribute__((ext_vector_type(4)));

#define BM 128
#define BN 128
#define BK 64

// async global->LDS, 16B per lane; LDS dest = wave-uniform base + lane*16
__device__ inline void glds16(const __bf16* g, __bf16* l) {
    __builtin_amdgcn_global_load_lds(
        (const __attribute__((address_space(1))) unsigned int*)g,
        (__attribute__((address_space(3))) unsigned int*)l,
        16, 0, 0);
}

// C = A @ B^T. A: [M,K] bf16 row-major. B: [N,K] bf16 row-major (B^T input).
// EPI 0: Cb = bf16(acc + bias)
// EPI 1: V transposed bf16 store (+bias)
// EPI 2: fused QKV projection: role = blockIdx.y>>3 (0:Q +bq, 1:K +bk,
//        2: V transposed +bv); col0 = (blockIdx.y&7)*BN; B += role*2^20
// EPI 3: Cf = acc (fp32)
// EPI 4: Cb = bf16(acc * scale)
template <int EPI>
__global__ __launch_bounds__(256) void gemm_bt(
    const __bf16* __restrict__ A, const __bf16* __restrict__ B,
    float* __restrict__ Cf, __bf16* __restrict__ Cb,
    const float* __restrict__ bias,
    int M, int N, int K, float scale,
    long sA, long sB, long sC,
    __bf16* __restrict__ Cb2, __bf16* __restrict__ Cb3,
    const float* __restrict__ bias2, const float* __restrict__ bias3)
{
    A += (long)blockIdx.z * sA;
    B += (long)blockIdx.z * sB;
    if (EPI == 3) Cf += (long)blockIdx.z * sC;
    if (EPI == 4) Cb += (long)blockIdx.z * sC;

    int role = 0;
    int col0;
    if (EPI == 2) {
        role = blockIdx.y >> 3;            // 0:Q 1:K 2:V  (wave-uniform)
        B += (size_t)role * (1u << 20);    // Wt panel for this matrix
        col0 = (blockIdx.y & 7) * BN;
        if (role == 1) { Cb = Cb2; bias = bias2; }
        if (role == 2) { Cb = Cb3; bias = bias3; }
    } else {
        col0 = blockIdx.y * BN;
    }

    __shared__ __align__(16) char smraw[65536];   // 2 x (A 16K + B 16K)
    float* smC = (float*)smraw;                   // [32][132] epilogue view

    const int t = threadIdx.x;
    const int w = t >> 6;          // wave 0..3
    const int l = t & 63;          // lane
    const int row0 = blockIdx.x * BM;
    const int wm = (w >> 1) * 64;  // wave's 64x64 quadrant
    const int wn = (w & 1) * 64;

    const int srow = l >> 3;                       // 0..7 row within chunk
    const int skel = (((l & 7) ^ srow) & 7) * 8;   // SWIZZLED global chunk offset

    const int lm = l & 15;
    const int g16 = l >> 4;        // 16-lane group 0..3
    const int sx = lm & 7;         // row swizzle key

    f32x4 acc[4][4];
#pragma unroll
    for (int i = 0; i < 4; i++)
#pragma unroll
        for (int j = 0; j < 4; j++) acc[i][j] = (f32x4){0.f, 0.f, 0.f, 0.f};

    auto stage = [&](int buf, int kt) {
        __bf16* sA = (__bf16*)(smraw + buf * 32768);
        __bf16* sB = sA + BM * BK;
#pragma unroll
        for (int i = 0; i < 4; i++) {
            const int chunk = i * 4 + w;
            const int r = chunk * 8 + srow;
            glds16(A + (size_t)(row0 + r) * K + kt + skel, &sA[chunk * 512]);
            glds16(B + (size_t)(col0 + r) * K + kt + skel, &sB[chunk * 512]);
        }
    };

    stage(0, 0);                 // prologue
    int cur = 0;
    for (int kt = 0; kt < K; kt += BK) {
        __syncthreads();         // buf[cur] loads landed during prev compute
        if (kt + BK < K) stage(cur ^ 1, kt + BK);

        const __bf16* sA = (const __bf16*)(smraw + cur * 32768);
        const __bf16* sB = sA + BM * BK;
#pragma unroll
        for (int ks = 0; ks < 2; ks++) {
            bf16x8 af[4], bg[4];
            const int p = ((ks * 4 + g16) ^ sx) * 8;   // swizzled position
#pragma unroll
            for (int mt = 0; mt < 4; mt++)
                af[mt] = *(const bf16x8*)&sA[(wm + mt * 16 + lm) * BK + p];
#pragma unroll
            for (int nt = 0; nt < 4; nt++)
                bg[nt] = *(const bf16x8*)&sB[(wn + nt * 16 + lm) * BK + p];
#pragma unroll
            for (int mt = 0; mt < 4; mt++)
#pragma unroll
                for (int nt = 0; nt < 4; nt++)
                    acc[mt][nt] = __builtin_amdgcn_mfma_f32_16x16x32_bf16(
                        af[mt], bg[nt], acc[mt][nt], 0, 0, 0);
        }
        cur ^= 1;
    }
    __syncthreads();             // all reads done before smC aliasing

    // ---- epilogue: stage C through LDS, emit coalesced global IO ----
    // C/D layout col=lane&15, row=(lane>>4)*4+i  [m91-verified]
    const int rl = (l >> 4) * 4;
    float breg[4];
    if (EPI <= 2) {
#pragma unroll
        for (int nt = 0; nt < 4; nt++) breg[nt] = bias[col0 + wn + nt * 16 + lm];
    }
#pragma unroll
    for (int mt = 0; mt < 4; mt++) {
        // write phase: 32 rows (two 16-row groups) x 128 cols into smC[32][132]
#pragma unroll
        for (int nt = 0; nt < 4; nt++)
#pragma unroll
            for (int i = 0; i < 4; i++) {
                const int lr = (w >> 1) * 16 + rl + i;   // 0..31
                const int c  = wn + nt * 16 + lm;        // 0..127
                float v = acc[mt][nt][i];
                if (EPI <= 2) v += breg[nt];
                if (EPI == 4) v *= scale;
                smC[lr * 132 + c] = v;
            }
        __syncthreads();

        if (EPI == 1 || (EPI == 2 && role == 2)) {
            // transposed store: Vt[batch][d][s], 64B segments per d
#pragma unroll
            for (int k = 0; k < 4; k++) {
                const int d  = (t >> 3) + 32 * k;        // 0..127
                const int sc = (t & 7) * 4;              // 0..28 (stays in 16-group)
                const int gr = row0 + mt * 16 + (sc & 15) + (sc >> 4) * 64;
                bf16x4 o;
#pragma unroll
                for (int j = 0; j < 4; j++) o[j] = (__bf16)smC[(sc + j) * 132 + d];
                *(bf16x4*)&Cb[(size_t)(gr >> 11) * ((size_t)N * 2048)
                              + (size_t)(col0 + d) * 2048 + (gr & 2047)] = o;
            }
        } else {
#pragma unroll
            for (int k = 0; k < 4; k++) {
                const int lr = (t >> 5) + 8 * k;         // 0..31
                const int c4 = (t & 31) * 4;             // 0..124
                const int gr = row0 + mt * 16 + (lr & 15) + (lr >> 4) * 64;
                const float4 v = *(const float4*)&smC[lr * 132 + c4];
                if (EPI == 3) {
                    *(float4*)&Cf[(size_t)gr * N + col0 + c4] = v;
                } else {
                    bf16x4 o = {(__bf16)v.x, (__bf16)v.y, (__bf16)v.z, (__bf16)v.w};
                    *(bf16x4*)&Cb[(size_t)gr * N + col0 + c4] = o;
                }
            }
        }
        __syncthreads();
    }
}

// Fused casts, one dispatch:
//   blocks [0,4096):    x fp32 [8192,1024] -> xb bf16 (8 floats/thread)
//   blocks [4096,7168): Wq/Wk/Wv fp32 [E,D] -> Wt bf16 [D,E] transposed,
//                       1024 blocks per matrix, 32x32 tile each
__global__ __launch_bounds__(256) void cast_all(
    const float* __restrict__ X, __bf16* __restrict__ Y,
    const float* __restrict__ Wq, const float* __restrict__ Wk,
    const float* __restrict__ Wv, __bf16* __restrict__ Wt)
{
    __shared__ float tile[32][33];
    const int t = threadIdx.x;
    if (blockIdx.x < 4096) {
        const size_t i = (size_t)blockIdx.x * 256 + t;
        const float4* X4 = (const float4*)X;
        const float4 a = X4[i * 2], b = X4[i * 2 + 1];
        bf16x8 o = {(__bf16)a.x, (__bf16)a.y, (__bf16)a.z, (__bf16)a.w,
                    (__bf16)b.x, (__bf16)b.y, (__bf16)b.z, (__bf16)b.w};
        ((bf16x8*)Y)[i] = o;
    } else {
        const int b = blockIdx.x - 4096;     // 0..3071
        const int z = b >> 10;               // matrix 0..2
        const int bb = b & 1023;             // 32x32 tile grid
        const float* W = z == 0 ? Wq : (z == 1 ? Wk : Wv);
        __bf16* O = Wt + (size_t)z * 1024 * 1024;
        const int tx = t & 31, ty = t >> 5;  // 32x8 thread tile
        const int d0 = (bb & 31) * 32, e0 = (bb >> 5) * 32;
#pragma unroll
        for (int j = 0; j < 32; j += 8)
            tile[ty + j][tx] = W[(size_t)(e0 + ty + j) * 1024 + d0 + tx];
        __syncthreads();
#pragma unroll
        for (int j = 0; j < 32; j += 8)
            O[(size_t)(d0 + ty + j) * 1024 + e0 + tx] = (__bf16)tile[tx][ty + j];
    }
}

// one block per row of 2048; S bf16 + mask int32 -> P bf16
// masked-out -> -1e30 (finite sentinel; matches prior passing behavior)
__global__ __launch_bounds__(256) void softmax_rows(const __bf16* __restrict__ S,
                                                    const int* __restrict__ mask,
                                                    __bf16* __restrict__ P) {
    const size_t row = blockIdx.x;
    const int t = threadIdx.x;
    const int w = t >> 6, l = t & 63;
    const bf16x8 s8 = ((const bf16x8*)(S + row * 2048))[t];
    const int4 mk0 = ((const int4*)(mask + row * 2048))[t * 2];
    const int4 mk1 = ((const int4*)(mask + row * 2048))[t * 2 + 1];
    float v[8];
    v[0] = mk0.x ? (float)s8[0] : -1e30f;
    v[1] = mk0.y ? (float)s8[1] : -1e30f;
    v[2] = mk0.z ? (float)s8[2] : -1e30f;
    v[3] = mk0.w ? (float)s8[3] : -1e30f;
    v[4] = mk1.x ? (float)s8[4] : -1e30f;
    v[5] = mk1.y ? (float)s8[5] : -1e30f;
    v[6] = mk1.z ? (float)s8[6] : -1e30f;
    v[7] = mk1.w ? (float)s8[7] : -1e30f;
    float m = v[0];
#pragma unroll
    for (int i = 1; i < 8; i++) m = fmaxf(m, v[i]);
#pragma unroll
    for (int off = 32; off; off >>= 1) m = fmaxf(m, __shfl_xor(m, off, 64));
    __shared__ float rm[4], rs[4];
    if (l == 0) rm[w] = m;
    __syncthreads();
    m = fmaxf(fmaxf(rm[0], rm[1]), fmaxf(rm[2], rm[3]));
    float e[8], sum = 0.f;
#pragma unroll
    for (int i = 0; i < 8; i++) { e[i] = __expf(v[i] - m); sum += e[i]; }
#pragma unroll
    for (int off = 32; off; off >>= 1) sum += __shfl_xor(sum, off, 64);
    if (l == 0) rs[w] = sum;
    __syncthreads();
    const float inv = 1.f / (rs[0] + rs[1] + rs[2] + rs[3]);
    bf16x8 o;
#pragma unroll
    for (int i = 0; i < 8; i++) o[i] = (__bf16)(e[i] * inv);
    ((bf16x8*)(P + row * 2048))[t] = o;
}

extern "C" void kernel_launch(void* const* d_in, const int* in_sizes, int n_in,
                              void* d_out, int out_size, void* d_ws, size_t ws_size,
                              hipStream_t stream) {
    const float* x  = (const float*)d_in[0];
    const int* mask = (const int*)d_in[1];
    const float* Wq = (const float*)d_in[2];
    const float* bq = (const float*)d_in[3];
    const float* Wk = (const float*)d_in[4];
    const float* bk = (const float*)d_in[5];
    const float* Wv = (const float*)d_in[6];
    const float* bv = (const float*)d_in[7];
    float* out = (float*)d_out;

    char* ws = (char*)d_ws;
    __bf16* xb = (__bf16*)(ws);                        // 16 MB
    __bf16* Wt = (__bf16*)(ws + (16ull << 20));        //  6 MB
    __bf16* Qb = (__bf16*)(ws + (22ull << 20));        // 16 MB
    __bf16* Kb = (__bf16*)(ws + (38ull << 20));        // 16 MB
    __bf16* Vt = (__bf16*)(ws + (54ull << 20));        // 16 MB
    __bf16* Sf = (__bf16*)(ws + (70ull << 20));        // 32 MB (bf16)
    __bf16* Pb = (__bf16*)(ws + (22ull << 20));        // 32 MB, aliases Qb+Kb (dead)

    // 1. fused casts
    cast_all<<<7168, 256, 0, stream>>>(x, xb, Wq, Wk, Wv, Wt);

    // 2. fused Q/K/V projections: M=8192, N=1024 per role, K=1024
    gemm_bt<2><<<dim3(64, 24, 1), 256, 0, stream>>>(
        xb, Wt, nullptr, Qb, bq, 8192, 1024, 1024, 1.f, 0, 0, 0,
        Kb, Vt, bk, bv);

    // 3. scores: per batch, M=N=2048, K=1024 -> bf16 Sf, scale folded
    gemm_bt<4><<<dim3(16, 16, 4), 256, 0, stream>>>(
        Qb, Kb, nullptr, Sf, nullptr, 2048, 2048, 1024, 1.0f / 1024.0f,
        2048L * 1024, 2048L * 1024, 2048L * 2048,
        nullptr, nullptr, nullptr, nullptr);

    // 4. softmax (mask applied here, read exactly once)
    softmax_rows<<<8192, 256, 0, stream>>>(Sf, mask, Pb);

    // 5. out = P @ V: per batch, M=2048, N=1024, K=2048
    gemm_bt<3><<<dim3(16, 8, 4), 256, 0, stream>>>(
        Pb, Vt, out, nullptr, nullptr, 2048, 1024, 2048, 1.f,
        2048L * 2048, 1024L * 2048, 2048L * 1024,
        nullptr, nullptr, nullptr, nullptr);
}